// Round 14
// baseline (224.972 us; speedup 1.0000x reference)
//
#include <hip/hip_runtime.h>

typedef _Float16 h8 __attribute__((ext_vector_type(8)));
typedef _Float16 h4 __attribute__((ext_vector_type(4)));
typedef _Float16 h2 __attribute__((ext_vector_type(2)));

// Problem constants (reference: B,M,N,L,S,KERN = 4,256,256,24,22,256; KERN==M → tile is identity)
constexpr int B_ = 4, M_ = 256, N_ = 256, L_ = 24, S_ = 22;
constexpr int SP_  = 24;    // shots padded to 24 (2 zero rows) for clean s-quads
constexpr int AP_  = 257;   // A4 [s][n] row pitch in h4 units (odd -> b64 reads 2-way, free)
constexpr int XTP_ = 25;    // XT2 [n][l] row pitch in h2 (4B) cells (25-dword stride, conflict-free)
constexpr int NYR_ = 280;   // Y rows per b-plane (279 used: 256 main + 23 tail)

// LDS layout (bytes) — sized for 2 blocks/CU (<= 81,920 each):
constexpr int A4_BYTES = SP_ * AP_ * 8;            // 49,344  A[s][n] h4 over c
constexpr int XT_BYTES = N_ * XTP_ * 4;            // 25,600  x[n][l] h2 over this block's b-pair
constexpr int Y_BYTES  = 2 * NYR_ * 8;             //  4,480  Y[b-half][n'] h4 planes, ONE sq at a time
constexpr int XT_OFF   = A4_BYTES;                 // 49,344
constexpr int Y_OFF    = XT_OFF + XT_BYTES;        // 74,944 (16B-aligned)
constexpr int WMAX_OFF = Y_OFF + Y_BYTES;          // 79,424
constexpr int LDS_BYTES = WMAX_OFF + 32;           // 79,456 <= 81,920  -> 2 blocks/CU
constexpr int XT_OFF_H2 = XT_OFF / 4;              // 12,336
constexpr int Y_OFF_H4  = Y_OFF / 8;               //  9,368

// Color bases as COMPILE-TIME constants (validated R6/R8/R9/R10):
constexpr float FR[L_] = {  // mu = 620
    6.252150e-05f, 1.904358e-04f, 5.418690e-04f, 1.440515e-03f, 3.577400e-03f,
    8.299750e-03f, 1.798893e-02f, 3.642490e-02f, 6.890060e-02f, 1.217600e-01f,
    2.010120e-01f, 3.100190e-01f, 4.466857e-01f, 6.012587e-01f, 7.560710e-01f,
    8.881955e-01f, 9.747661e-01f, 9.993953e-01f, 9.572367e-01f, 8.565352e-01f,
    7.160078e-01f, 5.591580e-01f, 4.079402e-01f, 2.780373e-01f};
constexpr float FG[L_] = {  // mu = 550
    1.110900e-02f, 2.348440e-02f, 4.638000e-02f, 8.557090e-02f, 1.474900e-01f,
    2.374920e-01f, 3.572560e-01f, 5.020580e-01f, 6.591400e-01f, 8.084270e-01f,
    9.262975e-01f, 9.915296e-01f, 9.915296e-01f, 9.262975e-01f, 8.084270e-01f,
    6.591400e-01f, 5.020580e-01f, 3.572560e-01f, 2.374920e-01f, 1.474900e-01f,
    8.557090e-02f, 4.638000e-02f, 2.348440e-02f, 1.110900e-02f};
constexpr float FB[L_] = {  // mu = 450 (pairs with wb)
    6.065307e-01f, 7.609727e-01f, 8.919300e-01f, 9.766475e-01f, 9.990553e-01f,
    9.547420e-01f, 8.523698e-01f, 7.109096e-01f, 5.539184e-01f, 4.032022e-01f,
    2.741855e-01f, 1.741852e-01f, 1.033776e-01f, 5.731640e-02f, 2.968800e-02f,
    1.436580e-02f, 6.494090e-03f, 2.742560e-03f, 1.079230e-03f, 3.988070e-04f,
    1.369660e-04f, 4.417250e-05f, 1.327420e-05f, 3.726650e-06f};
constexpr float FC[L_] = {  // mu = 500 (pairs with wc)
    1.353353e-01f, 2.204053e-01f, 3.353338e-01f, 4.766271e-01f, 6.328849e-01f,
    7.850828e-01f, 9.098110e-01f, 9.849909e-01f, 9.962264e-01f, 9.413024e-01f,
    8.308921e-01f, 6.851808e-01f, 5.278508e-01f, 3.798934e-01f, 2.554222e-01f,
    1.604349e-01f, 9.414200e-02f, 5.160780e-02f, 2.642960e-02f, 1.264440e-02f,
    5.651680e-03f, 2.359870e-03f, 9.205430e-04f, 3.354630e-04f};

__device__ __forceinline__ float fdot2(h2 a, h2 b, float c) {
    return __builtin_amdgcn_fdot2(a, b, c, false);
}

// R23: attribute route is dead (5 inert spellings; VGPR stuck at 232 =
// elastic use of the 65536/wg budget; occupancy 10.5% shows a 232-reg
// 4-wave block blocks the 2nd block from packing). Use the allocator's
// rigidity FOR us: wg=512 -> budget exactly 128, where HW packs 16
// waves/CU (m69). R13-R18 spilled at 128 with ~160 demand; this splits
// the R21 structure's b-pair across thread halves (th = t>>8 owns
// b = 2bp+th): X acc 48->24, A-pass acc 16->8, xq h2->u16 scalar.
// Demand ~90-110 <= 128 -> no spill. LDS unchanged 79,456B -> 2 blocks/CU
// -> 16 waves/CU = 4 waves/SIMD (4x R22's latency hiding). Y becomes two
// per-b planes (conflict-free split reads); staging parallelized (th0: x,
// th1: weights); light A-pass sched_barriers as hoist insurance (R17).
// Falsifiers: WRITE >> 30MB = spill (demand model wrong); occupancy
// <= 20% with VGPR <= 128 = packing blocked elsewhere.
__global__ __launch_bounds__(512)
void cassi_fused(
    const float* __restrict__ x,
    const float* __restrict__ wr, const float* __restrict__ wg,
    const float* __restrict__ wb, const float* __restrict__ wc,
    float* __restrict__ out, float* __restrict__ bmax_out)
{
    __shared__ __align__(16) char lds_raw[LDS_BYTES];
    h4* A4  = reinterpret_cast<h4*>(lds_raw);
    h2* XT2 = reinterpret_cast<h2*>(lds_raw) + XT_OFF_H2;             // staging (b-pairs)
    const _Float16* XTH = reinterpret_cast<const _Float16*>(lds_raw + XT_OFF); // scalar reads
    h4* Y4  = reinterpret_cast<h4*>(lds_raw) + Y_OFF_H4;              // 2 planes of NYR_ h4
    float* wmax = reinterpret_cast<float*>(lds_raw + WMAX_OFF);

    const int t  = threadIdx.x;
    const int tt = t & 255;              // column
    const int th = t >> 8;               // half: which b of the pair
    const int m  = blockIdx.x >> 1;      // row
    const int bp = blockIdx.x & 1;       // b-pair
    const int b  = 2 * bp + th;          // this thread's b

    // ---- Staging ----
    // zero A pad rows s=22,23 (514 h4): 512 threads + 2 guarded.
    {
        h4 z; z.x = z.y = z.z = z.w = (_Float16)0.f;
        A4[S_ * AP_ + t] = z;
        if (t < 2) A4[S_ * AP_ + 512 + t] = z;
    }
    if (th == 0) {
        // x: thread tt stages column n=tt for BOTH b of the pair -> h2 cells.
        const float4* xa = reinterpret_cast<const float4*>(x + (((2*bp    ) * M_ + m) * N_ + tt) * L_);
        const float4* xb = reinterpret_cast<const float4*>(x + (((2*bp + 1) * M_ + m) * N_ + tt) * L_);
        #pragma unroll
        for (int i = 0; i < 6; ++i) {
            const float4 va = xa[i], vb = xb[i];
            h2 c0; c0.x=(_Float16)va.x; c0.y=(_Float16)vb.x;
            h2 c1; c1.x=(_Float16)va.y; c1.y=(_Float16)vb.y;
            h2 c2; c2.x=(_Float16)va.z; c2.y=(_Float16)vb.z;
            h2 c3; c3.x=(_Float16)va.w; c3.y=(_Float16)vb.w;
            XT2[tt * XTP_ + 4 * i + 0] = c0;
            XT2[tt * XTP_ + 4 * i + 1] = c1;
            XT2[tt * XTP_ + 4 * i + 2] = c2;
            XT2[tt * XTP_ + 4 * i + 3] = c3;
            __builtin_amdgcn_sched_barrier(0);
        }
    } else {
        // weights: coalesced, normalized once, h4-packed A[s][n].
        const float* wrm = wr + m * (N_ * S_);
        const float* wgm = wg + m * (N_ * S_);
        const float* wbm = wb + m * (N_ * S_);
        const float* wcm = wc + m * (N_ * S_);
        #pragma unroll 1
        for (int i = 0; i < S_; ++i) {
            const int f = i * 256 + tt;
            const float r = wrm[f], g = wgm[f], u = wbm[f], v = wcm[f];
            const int n = f / S_, s = f - n * S_;
            const float inv = 1.f / (r + g + u + v);
            h4 p;
            p.x = (_Float16)(r * inv); p.y = (_Float16)(g * inv);
            p.z = (_Float16)(u * inv); p.w = (_Float16)(v * inv);
            A4[s * AP_ + n] = p;
        }
    }
    __syncthreads();

    // ---- 6 alternating pass pairs: A(sq) fills this b's Y plane, B(sq)
    // consumes it. X acc (24 regs) lives across all passes.
    float X[L_];
    #pragma unroll
    for (int l = 0; l < L_; ++l) X[l] = 0.f;
    float vmax = 0.f;
    h4* Yp = Y4 + th * NYR_;    // this b's plane

    #pragma unroll 1
    for (int sq = 0; sq < 6; ++sq) {
        // ---- A-pass: Y[n'] for this b, this sq. Waves 0 (th0) and 4 (th1)
        // (tt<64) run dual main+tail; others lean (idx = tt-l >= 41).
        if (tt < 64) {
            float4 aM, aT;
            aM.x=aM.y=aM.z=aM.w=0.f; aT=aM;
            #pragma unroll
            for (int l = 0; l < L_; ++l) {
                h2 f01; f01.x = (_Float16)FR[l]; f01.y = (_Float16)FG[l];
                h2 f23; f23.x = (_Float16)FB[l]; f23.y = (_Float16)FC[l];
                const bool mn = (l <= tt);
                const int idx = mn ? (tt - l) : (256 + tt - l);
                const float mm = mn ? 1.f : 0.f;
                const int ab = (4 * sq) * AP_ + idx;
                const h4 p0 = A4[ab], p1 = A4[ab + AP_], p2 = A4[ab + 2 * AP_], p3 = A4[ab + 3 * AP_];
                const float xv = (float)XTH[(idx * XTP_ + l) * 2 + th];
                const float g0 = fdot2(h2{p0.x,p0.y}, f01, fdot2(h2{p0.z,p0.w}, f23, 0.f));
                const float g1 = fdot2(h2{p1.x,p1.y}, f01, fdot2(h2{p1.z,p1.w}, f23, 0.f));
                const float g2 = fdot2(h2{p2.x,p2.y}, f01, fdot2(h2{p2.z,p2.w}, f23, 0.f));
                const float g3 = fdot2(h2{p3.x,p3.y}, f01, fdot2(h2{p3.z,p3.w}, f23, 0.f));
                const float gm0 = g0 * mm, gt0 = g0 - gm0;
                const float gm1 = g1 * mm, gt1 = g1 - gm1;
                const float gm2 = g2 * mm, gt2 = g2 - gm2;
                const float gm3 = g3 * mm, gt3 = g3 - gm3;
                aM.x += gm0 * xv; aT.x += gt0 * xv;
                aM.y += gm1 * xv; aT.y += gt1 * xv;
                aM.z += gm2 * xv; aT.z += gt2 * xv;
                aM.w += gm3 * xv; aT.w += gt3 * xv;
                if ((l & 3) == 3) __builtin_amdgcn_sched_barrier(0);
            }
            h4 pm;
            pm.x=(_Float16)aM.x; pm.y=(_Float16)aM.y; pm.z=(_Float16)aM.z; pm.w=(_Float16)aM.w;
            Yp[tt] = pm;
            if (tt < 23) {
                h4 pt;
                pt.x=(_Float16)aT.x; pt.y=(_Float16)aT.y; pt.z=(_Float16)aT.z; pt.w=(_Float16)aT.w;
                Yp[256 + tt] = pt;
            }
        } else {
            float4 aM;
            aM.x=aM.y=aM.z=aM.w=0.f;
            #pragma unroll
            for (int l = 0; l < L_; ++l) {
                h2 f01; f01.x = (_Float16)FR[l]; f01.y = (_Float16)FG[l];
                h2 f23; f23.x = (_Float16)FB[l]; f23.y = (_Float16)FC[l];
                const int idx = tt - l;      // tt >= 64 -> always >= 41
                const int ab = (4 * sq) * AP_ + idx;
                const h4 p0 = A4[ab], p1 = A4[ab + AP_], p2 = A4[ab + 2 * AP_], p3 = A4[ab + 3 * AP_];
                const float xv = (float)XTH[(idx * XTP_ + l) * 2 + th];
                const float g0 = fdot2(h2{p0.x,p0.y}, f01, fdot2(h2{p0.z,p0.w}, f23, 0.f));
                const float g1 = fdot2(h2{p1.x,p1.y}, f01, fdot2(h2{p1.z,p1.w}, f23, 0.f));
                const float g2 = fdot2(h2{p2.x,p2.y}, f01, fdot2(h2{p2.z,p2.w}, f23, 0.f));
                const float g3 = fdot2(h2{p3.x,p3.y}, f01, fdot2(h2{p3.z,p3.w}, f23, 0.f));
                aM.x += g0 * xv;
                aM.y += g1 * xv;
                aM.z += g2 * xv;
                aM.w += g3 * xv;
                if ((l & 3) == 3) __builtin_amdgcn_sched_barrier(0);
            }
            h4 pm;
            pm.x=(_Float16)aM.x; pm.y=(_Float16)aM.y; pm.z=(_Float16)aM.z; pm.w=(_Float16)aM.w;
            Yp[tt] = pm;
        }
        __syncthreads();

        // ---- B-pass: X[tt][l] += this sq's 4 shots for this b.
        {
            const int ab = (4 * sq) * AP_ + tt;
            const h4 q0 = A4[ab], q1 = A4[ab + AP_], q2 = A4[ab + 2 * AP_], q3 = A4[ab + 3 * AP_];
            #pragma unroll
            for (int l = 0; l < L_; ++l) {
                h2 f01; f01.x = (_Float16)FR[l]; f01.y = (_Float16)FG[l];
                h2 f23; f23.x = (_Float16)FB[l]; f23.y = (_Float16)FC[l];
                const float g0 = fdot2(h2{q0.x,q0.y}, f01, fdot2(h2{q0.z,q0.w}, f23, 0.f));
                const float g1 = fdot2(h2{q1.x,q1.y}, f01, fdot2(h2{q1.z,q1.w}, f23, 0.f));
                const float g2 = fdot2(h2{q2.x,q2.y}, f01, fdot2(h2{q2.z,q2.w}, f23, 0.f));
                const float g3 = fdot2(h2{q3.x,q3.y}, f01, fdot2(h2{q3.z,q3.w}, f23, 0.f));
                h2 G01; G01.x = (_Float16)g0; G01.y = (_Float16)g1;
                h2 G23; G23.x = (_Float16)g2; G23.y = (_Float16)g3;
                const h4 y = Yp[tt + l];
                X[l] = fdot2(G01, h2{y.x,y.y}, fdot2(G23, h2{y.z,y.w}, X[l]));
            }
        }
        __syncthreads();   // Y plane free for next sq
    }

    // ---- Output: contiguous 96B burst for this (b, row tt) + running max.
    {
        float4* o = reinterpret_cast<float4*>(out + ((b * M_ + m) * N_ + tt) * L_);
        #pragma unroll
        for (int i = 0; i < 6; ++i) {
            float4 v;
            v.x = X[4*i+0]; v.y = X[4*i+1]; v.z = X[4*i+2]; v.w = X[4*i+3];
            vmax = fmaxf(vmax, fmaxf(fmaxf(v.x, v.y), fmaxf(v.z, v.w)));
            o[i] = v;
        }
    }

    #pragma unroll
    for (int off = 32; off > 0; off >>= 1)
        vmax = fmaxf(vmax, __shfl_xor(vmax, off, 64));
    if ((t & 63) == 0) wmax[t >> 6] = vmax;
    __syncthreads();
    if (t == 0) {
        float v = wmax[0];
        #pragma unroll
        for (int w = 1; w < 8; ++w) v = fmaxf(v, wmax[w]);
        bmax_out[blockIdx.x] = v;
    }
}

// Normalize; each block re-reduces the 512 per-block maxes itself.
__global__ __launch_bounds__(256) void cassi_norm(float* __restrict__ out,
                                                  const float* __restrict__ bmax)
{
    __shared__ float wm[4];
    const int t = threadIdx.x;
    float v = fmaxf(bmax[t], bmax[t + 256]);
    #pragma unroll
    for (int off = 32; off > 0; off >>= 1)
        v = fmaxf(v, __shfl_xor(v, off, 64));
    if ((t & 63) == 0) wm[t >> 6] = v;
    __syncthreads();
    const float inv = 1.f / fmaxf(fmaxf(wm[0], wm[1]), fmaxf(wm[2], wm[3]));
    const int i = (blockIdx.x * 256 + t) * 4;
    float4 q = *reinterpret_cast<float4*>(out + i);
    q.x *= inv; q.y *= inv; q.z *= inv; q.w *= inv;
    *reinterpret_cast<float4*>(out + i) = q;
}

extern "C" void kernel_launch(void* const* d_in, const int* in_sizes, int n_in,
                              void* d_out, int out_size, void* d_ws, size_t ws_size,
                              hipStream_t stream) {
    const float* x  = (const float*)d_in[0];
    const float* wr = (const float*)d_in[1];
    const float* wg = (const float*)d_in[2];
    const float* wb = (const float*)d_in[3];
    const float* wc = (const float*)d_in[4];
    float* out  = (float*)d_out;
    float* bmax = (float*)d_ws;          // 512 per-block maxes (2KB)

    cassi_fused<<<2 * M_, 512, 0, stream>>>(x, wr, wg, wb, wc, out, bmax);
    const int n4blocks = (B_ * M_ * N_ * L_) / 4 / 256;     // 6144, exact
    cassi_norm<<<n4blocks, 256, 0, stream>>>(out, bmax);
}

// Round 15
// 218.332 us; speedup vs baseline: 1.0304x; 1.0304x over previous
//
#include <hip/hip_runtime.h>

typedef _Float16 h8 __attribute__((ext_vector_type(8)));
typedef _Float16 h4 __attribute__((ext_vector_type(4)));
typedef _Float16 h2 __attribute__((ext_vector_type(2)));

// Problem constants (reference: B,M,N,L,S,KERN = 4,256,256,24,22,256; KERN==M → tile is identity)
constexpr int B_ = 4, M_ = 256, N_ = 256, L_ = 24, S_ = 22;
constexpr int SP_  = 24;    // shots padded to 24 (2 zero rows) for clean s-quads
constexpr int AP_  = 257;   // A4 [s][n] row pitch in h4 units (odd -> b64 reads 2-way, free)
constexpr int XTP2_ = 13;   // XT2 [n] row pitch in h2 (4B) cells; 13 dwords, odd -> 2-way, free
constexpr int NYR_ = 280;   // Y rows (279 used: 256 main + 23 tail)

// LDS layout (bytes) — single-b block, sized well under 80KB for 2 blocks/CU:
constexpr int A4_BYTES = SP_ * AP_ * 8;            // 49,344  A[s][n] h4 over c
constexpr int XT_BYTES = N_ * XTP2_ * 4;           // 13,312  x[n][l] _Float16, this block's b only
constexpr int Y_BYTES  = NYR_ * 8;                 //  2,240  Y[n'] h4 (4 shots of current sq)
constexpr int XT_OFF   = A4_BYTES;                 // 49,344
constexpr int Y_OFF    = XT_OFF + XT_BYTES;        // 62,656 (16B-aligned)
constexpr int WMAX_OFF = Y_OFF + Y_BYTES;          // 64,896
constexpr int LDS_BYTES = WMAX_OFF + 32;           // 64,928  -> 2 blocks/CU trivially on LDS
constexpr int XT_OFF_H2 = XT_OFF / 4;              // 12,336
constexpr int Y_OFF_H4  = Y_OFF / 8;               //  7,832

// Color bases as COMPILE-TIME constants (validated R6/R8/R9/R10):
constexpr float FR[L_] = {  // mu = 620
    6.252150e-05f, 1.904358e-04f, 5.418690e-04f, 1.440515e-03f, 3.577400e-03f,
    8.299750e-03f, 1.798893e-02f, 3.642490e-02f, 6.890060e-02f, 1.217600e-01f,
    2.010120e-01f, 3.100190e-01f, 4.466857e-01f, 6.012587e-01f, 7.560710e-01f,
    8.881955e-01f, 9.747661e-01f, 9.993953e-01f, 9.572367e-01f, 8.565352e-01f,
    7.160078e-01f, 5.591580e-01f, 4.079402e-01f, 2.780373e-01f};
constexpr float FG[L_] = {  // mu = 550
    1.110900e-02f, 2.348440e-02f, 4.638000e-02f, 8.557090e-02f, 1.474900e-01f,
    2.374920e-01f, 3.572560e-01f, 5.020580e-01f, 6.591400e-01f, 8.084270e-01f,
    9.262975e-01f, 9.915296e-01f, 9.915296e-01f, 9.262975e-01f, 8.084270e-01f,
    6.591400e-01f, 5.020580e-01f, 3.572560e-01f, 2.374920e-01f, 1.474900e-01f,
    8.557090e-02f, 4.638000e-02f, 2.348440e-02f, 1.110900e-02f};
constexpr float FB[L_] = {  // mu = 450 (pairs with wb)
    6.065307e-01f, 7.609727e-01f, 8.919300e-01f, 9.766475e-01f, 9.990553e-01f,
    9.547420e-01f, 8.523698e-01f, 7.109096e-01f, 5.539184e-01f, 4.032022e-01f,
    2.741855e-01f, 1.741852e-01f, 1.033776e-01f, 5.731640e-02f, 2.968800e-02f,
    1.436580e-02f, 6.494090e-03f, 2.742560e-03f, 1.079230e-03f, 3.988070e-04f,
    1.369660e-04f, 4.417250e-05f, 1.327420e-05f, 3.726650e-06f};
constexpr float FC[L_] = {  // mu = 500 (pairs with wc)
    1.353353e-01f, 2.204053e-01f, 3.353338e-01f, 4.766271e-01f, 6.328849e-01f,
    7.850828e-01f, 9.098110e-01f, 9.849909e-01f, 9.962264e-01f, 9.413024e-01f,
    8.308921e-01f, 6.851808e-01f, 5.278508e-01f, 3.798934e-01f, 2.554222e-01f,
    1.604349e-01f, 9.414200e-02f, 5.160780e-02f, 2.642960e-02f, 1.264440e-02f,
    5.651680e-03f, 2.359870e-03f, 9.205430e-04f, 3.354630e-04f};

__device__ __forceinline__ float fdot2(h2 a, h2 b, float c) {
    return __builtin_amdgcn_fdot2(a, b, c, false);
}

// R24: R23 killed wg=512 for good (budget 128 < demand ~150 even single-b:
// WRITE back to 110MB). Refined HW model: per-SIMD file = 512 VGPRs; at 256
// thr a block is 1 wave/SIMD, so 2-block co-residency needs reported VGPR
// <= 192 (2x192=384 <= 512). R21 missed at 232 because threads carried TWO
// b's (48 acc). R24: single-b blocks, grid 4*M=1024 (block = one (m,b)).
// Acc X[24] only; A-pass 8 regs; XT one b (13.3KB, pitch-13 dwords, 2-way
// free); Y one plane (2.2KB). LDS 64,928B (also clears any LDS-granule
// doubt). Demand ~130-180 -> quantum <=192 -> 2 blocks/CU = 2 waves/SIMD.
// Cost: weights staged 4x/row (L2-absorbed), G recomputed per-b (per-thread
// VALU actually DROPS ~20% vs R21; chip VALU x1.5 vs 25% busy = headroom).
// Falsifiers: VGPR ~232 -> elastic hoist, go surgical sched_barriers;
// occupancy ~10.5% with VGPR<=192 -> non-VGPR packing blocker, disasm next.
__global__ __launch_bounds__(256)
void cassi_fused(
    const float* __restrict__ x,
    const float* __restrict__ wr, const float* __restrict__ wg,
    const float* __restrict__ wb, const float* __restrict__ wc,
    float* __restrict__ out, float* __restrict__ bmax_out)
{
    __shared__ __align__(16) char lds_raw[LDS_BYTES];
    h4* A4  = reinterpret_cast<h4*>(lds_raw);
    h2* XT2 = reinterpret_cast<h2*>(lds_raw) + XT_OFF_H2;                      // staging view
    const _Float16* XTH = reinterpret_cast<const _Float16*>(lds_raw + XT_OFF); // read view: [n*26 + l]
    h4* Y4  = reinterpret_cast<h4*>(lds_raw) + Y_OFF_H4;                       // one plane
    float* wmax = reinterpret_cast<float*>(lds_raw + WMAX_OFF);

    const int t = threadIdx.x;           // 0..255: column
    const int m = blockIdx.x >> 2;       // row
    const int b = blockIdx.x & 3;        // this block's batch index

    // ---- Staging ----
    // zero A pad rows s=22,23 (514 h4): 256 threads x2 + 2 guarded.
    {
        h4 z; z.x = z.y = z.z = z.w = (_Float16)0.f;
        A4[S_ * AP_ + t] = z;
        A4[S_ * AP_ + 256 + t] = z;
        if (t < 2) A4[S_ * AP_ + 512 + t] = z;
    }
    // x: thread t stages column n=t for THIS block's b -> 12 h2 cells.
    {
        const float4* xb = reinterpret_cast<const float4*>(x + ((b * M_ + m) * N_ + t) * L_);
        #pragma unroll
        for (int i = 0; i < 6; ++i) {
            const float4 v = xb[i];
            h2 c0; c0.x = (_Float16)v.x; c0.y = (_Float16)v.y;
            h2 c1; c1.x = (_Float16)v.z; c1.y = (_Float16)v.w;
            XT2[t * XTP2_ + 2 * i + 0] = c0;
            XT2[t * XTP2_ + 2 * i + 1] = c1;
        }
    }
    // weights: coalesced, normalized once, h4-packed A[s][n] (all 4 blocks
    // of a row stage this; later readers hit L2/L3).
    {
        const float* wrm = wr + m * (N_ * S_);
        const float* wgm = wg + m * (N_ * S_);
        const float* wbm = wb + m * (N_ * S_);
        const float* wcm = wc + m * (N_ * S_);
        #pragma unroll 1
        for (int i = 0; i < S_; ++i) {
            const int f = i * 256 + t;
            const float r = wrm[f], g = wgm[f], u = wbm[f], v = wcm[f];
            const int n = f / S_, s = f - n * S_;
            const float inv = 1.f / (r + g + u + v);
            h4 p;
            p.x = (_Float16)(r * inv); p.y = (_Float16)(g * inv);
            p.z = (_Float16)(u * inv); p.w = (_Float16)(v * inv);
            A4[s * AP_ + n] = p;
        }
    }
    __syncthreads();

    // ---- 6 alternating pass pairs: A(sq) fills the Y plane, B(sq) consumes.
    // X acc (24 regs) lives across all passes.
    float X[L_];
    #pragma unroll
    for (int l = 0; l < L_; ++l) X[l] = 0.f;
    float vmax = 0.f;

    #pragma unroll 1
    for (int sq = 0; sq < 6; ++sq) {
        // ---- A-pass: Y[n'] for this sq. Wave 0 (t<64) dual main+tail;
        // waves 1-3 lean (idx = t-l always >= 41). Wave-uniform branch.
        if (t < 64) {
            float4 aM, aT;
            aM.x = aM.y = aM.z = aM.w = 0.f; aT = aM;
            #pragma unroll
            for (int l = 0; l < L_; ++l) {
                h2 f01; f01.x = (_Float16)FR[l]; f01.y = (_Float16)FG[l];
                h2 f23; f23.x = (_Float16)FB[l]; f23.y = (_Float16)FC[l];
                const bool mn = (l <= t);
                const int idx = mn ? (t - l) : (256 + t - l);
                const float mm = mn ? 1.f : 0.f;
                const int ab = (4 * sq) * AP_ + idx;
                const h4 p0 = A4[ab], p1 = A4[ab + AP_], p2 = A4[ab + 2 * AP_], p3 = A4[ab + 3 * AP_];
                const float xv = (float)XTH[idx * (2 * XTP2_) + l];
                const float g0 = fdot2(h2{p0.x,p0.y}, f01, fdot2(h2{p0.z,p0.w}, f23, 0.f));
                const float g1 = fdot2(h2{p1.x,p1.y}, f01, fdot2(h2{p1.z,p1.w}, f23, 0.f));
                const float g2 = fdot2(h2{p2.x,p2.y}, f01, fdot2(h2{p2.z,p2.w}, f23, 0.f));
                const float g3 = fdot2(h2{p3.x,p3.y}, f01, fdot2(h2{p3.z,p3.w}, f23, 0.f));
                const float gm0 = g0 * mm, gt0 = g0 - gm0;
                const float gm1 = g1 * mm, gt1 = g1 - gm1;
                const float gm2 = g2 * mm, gt2 = g2 - gm2;
                const float gm3 = g3 * mm, gt3 = g3 - gm3;
                aM.x += gm0 * xv; aT.x += gt0 * xv;
                aM.y += gm1 * xv; aT.y += gt1 * xv;
                aM.z += gm2 * xv; aT.z += gt2 * xv;
                aM.w += gm3 * xv; aT.w += gt3 * xv;
            }
            h4 pm;
            pm.x=(_Float16)aM.x; pm.y=(_Float16)aM.y; pm.z=(_Float16)aM.z; pm.w=(_Float16)aM.w;
            Y4[t] = pm;
            if (t < 23) {
                h4 pt;
                pt.x=(_Float16)aT.x; pt.y=(_Float16)aT.y; pt.z=(_Float16)aT.z; pt.w=(_Float16)aT.w;
                Y4[256 + t] = pt;
            }
        } else {
            float4 aM;
            aM.x = aM.y = aM.z = aM.w = 0.f;
            #pragma unroll
            for (int l = 0; l < L_; ++l) {
                h2 f01; f01.x = (_Float16)FR[l]; f01.y = (_Float16)FG[l];
                h2 f23; f23.x = (_Float16)FB[l]; f23.y = (_Float16)FC[l];
                const int idx = t - l;      // t >= 64 -> always >= 41
                const int ab = (4 * sq) * AP_ + idx;
                const h4 p0 = A4[ab], p1 = A4[ab + AP_], p2 = A4[ab + 2 * AP_], p3 = A4[ab + 3 * AP_];
                const float xv = (float)XTH[idx * (2 * XTP2_) + l];
                const float g0 = fdot2(h2{p0.x,p0.y}, f01, fdot2(h2{p0.z,p0.w}, f23, 0.f));
                const float g1 = fdot2(h2{p1.x,p1.y}, f01, fdot2(h2{p1.z,p1.w}, f23, 0.f));
                const float g2 = fdot2(h2{p2.x,p2.y}, f01, fdot2(h2{p2.z,p2.w}, f23, 0.f));
                const float g3 = fdot2(h2{p3.x,p3.y}, f01, fdot2(h2{p3.z,p3.w}, f23, 0.f));
                aM.x += g0 * xv;
                aM.y += g1 * xv;
                aM.z += g2 * xv;
                aM.w += g3 * xv;
            }
            h4 pm;
            pm.x=(_Float16)aM.x; pm.y=(_Float16)aM.y; pm.z=(_Float16)aM.z; pm.w=(_Float16)aM.w;
            Y4[t] = pm;
        }
        __syncthreads();

        // ---- B-pass: X[t][l] += this sq's 4 shots.
        {
            const int ab = (4 * sq) * AP_ + t;
            const h4 q0 = A4[ab], q1 = A4[ab + AP_], q2 = A4[ab + 2 * AP_], q3 = A4[ab + 3 * AP_];
            #pragma unroll
            for (int l = 0; l < L_; ++l) {
                h2 f01; f01.x = (_Float16)FR[l]; f01.y = (_Float16)FG[l];
                h2 f23; f23.x = (_Float16)FB[l]; f23.y = (_Float16)FC[l];
                const float g0 = fdot2(h2{q0.x,q0.y}, f01, fdot2(h2{q0.z,q0.w}, f23, 0.f));
                const float g1 = fdot2(h2{q1.x,q1.y}, f01, fdot2(h2{q1.z,q1.w}, f23, 0.f));
                const float g2 = fdot2(h2{q2.x,q2.y}, f01, fdot2(h2{q2.z,q2.w}, f23, 0.f));
                const float g3 = fdot2(h2{q3.x,q3.y}, f01, fdot2(h2{q3.z,q3.w}, f23, 0.f));
                h2 G01; G01.x = (_Float16)g0; G01.y = (_Float16)g1;
                h2 G23; G23.x = (_Float16)g2; G23.y = (_Float16)g3;
                const h4 y = Y4[t + l];
                X[l] = fdot2(G01, h2{y.x,y.y}, fdot2(G23, h2{y.z,y.w}, X[l]));
            }
        }
        __syncthreads();   // Y plane free for next sq
    }

    // ---- Output: contiguous 96B burst for this (b, row t) + running max.
    {
        float4* o = reinterpret_cast<float4*>(out + ((b * M_ + m) * N_ + t) * L_);
        #pragma unroll
        for (int i = 0; i < 6; ++i) {
            float4 v;
            v.x = X[4*i+0]; v.y = X[4*i+1]; v.z = X[4*i+2]; v.w = X[4*i+3];
            vmax = fmaxf(vmax, fmaxf(fmaxf(v.x, v.y), fmaxf(v.z, v.w)));
            o[i] = v;
        }
    }

    #pragma unroll
    for (int off = 32; off > 0; off >>= 1)
        vmax = fmaxf(vmax, __shfl_xor(vmax, off, 64));
    if ((t & 63) == 0) wmax[t >> 6] = vmax;
    __syncthreads();
    if (t == 0)
        bmax_out[blockIdx.x] = fmaxf(fmaxf(wmax[0], wmax[1]), fmaxf(wmax[2], wmax[3]));
}

// Normalize; each block re-reduces the 1024 per-block maxes itself.
__global__ __launch_bounds__(256) void cassi_norm(float* __restrict__ out,
                                                  const float* __restrict__ bmax)
{
    __shared__ float wm[4];
    const int t = threadIdx.x;
    float v = fmaxf(fmaxf(bmax[t], bmax[t + 256]),
                    fmaxf(bmax[t + 512], bmax[t + 768]));
    #pragma unroll
    for (int off = 32; off > 0; off >>= 1)
        v = fmaxf(v, __shfl_xor(v, off, 64));
    if ((t & 63) == 0) wm[t >> 6] = v;
    __syncthreads();
    const float inv = 1.f / fmaxf(fmaxf(wm[0], wm[1]), fmaxf(wm[2], wm[3]));
    const int i = (blockIdx.x * 256 + t) * 4;
    float4 q = *reinterpret_cast<float4*>(out + i);
    q.x *= inv; q.y *= inv; q.z *= inv; q.w *= inv;
    *reinterpret_cast<float4*>(out + i) = q;
}

extern "C" void kernel_launch(void* const* d_in, const int* in_sizes, int n_in,
                              void* d_out, int out_size, void* d_ws, size_t ws_size,
                              hipStream_t stream) {
    const float* x  = (const float*)d_in[0];
    const float* wr = (const float*)d_in[1];
    const float* wg = (const float*)d_in[2];
    const float* wb = (const float*)d_in[3];
    const float* wc = (const float*)d_in[4];
    float* out  = (float*)d_out;
    float* bmax = (float*)d_ws;          // 1024 per-block maxes (4KB)

    cassi_fused<<<4 * M_, 256, 0, stream>>>(x, wr, wg, wb, wc, out, bmax);
    const int n4blocks = (B_ * M_ * N_ * L_) / 4 / 256;     // 6144, exact
    cassi_norm<<<n4blocks, 256, 0, stream>>>(out, bmax);
}

// Round 16
// 195.447 us; speedup vs baseline: 1.1511x; 1.1171x over previous
//
#include <hip/hip_runtime.h>

typedef _Float16 h8 __attribute__((ext_vector_type(8)));
typedef _Float16 h4 __attribute__((ext_vector_type(4)));
typedef _Float16 h2 __attribute__((ext_vector_type(2)));

// Problem constants (reference: B,M,N,L,S,KERN = 4,256,256,24,22,256; KERN==M → tile is identity)
constexpr int B_ = 4, M_ = 256, N_ = 256, L_ = 24, S_ = 22;
constexpr int SP_  = 24;    // shots padded to 24 (2 zero rows) for clean s-quads
constexpr int AP_  = 257;   // A4 [s][n] row pitch in h4 units (odd -> b64 reads 2-way, free)
constexpr int XTP_ = 25;    // XT2 [n][l] row pitch in h2 (4B) cells (25-dword stride, conflict-free)
constexpr int NYR_ = 280;   // Y rows per plane (279 used: 256 main + 23 tail)

// LDS layout (bytes). Co-residency NEVER happens on this harness (empirical
// law from R21/R22/R24: occupancy always == 1 workgroup/CU regardless of
// VGPR 64..232 and LDS 65..154KB), so the 80KB 2-block budget is moot and
// Y can be double-buffered freely.
constexpr int A4_BYTES = SP_ * AP_ * 8;            // 49,344  A[s][n] h4 over c
constexpr int XT_BYTES = N_ * XTP_ * 4;            // 25,600  x[n][l] h2 over this block's b-pair
constexpr int Y_BYTES  = 2 * NYR_ * 16;            //  8,960  TWO Y planes (16B cells: 2 h4)
constexpr int XT_OFF   = A4_BYTES;                 // 49,344
constexpr int Y_OFF    = XT_OFF + XT_BYTES;        // 74,944 (16B-aligned)
constexpr int WMAX_OFF = Y_OFF + Y_BYTES;          // 83,904
constexpr int LDS_BYTES = WMAX_OFF + 32;           // 83,936 <= 163,840
constexpr int XT_OFF_H2 = XT_OFF / 4;              // 12,336
constexpr int Y_OFF_H4  = Y_OFF / 8;               //  9,368
constexpr int Y_OFF_H8  = Y_OFF / 16;              //  4,684

// Color bases as COMPILE-TIME constants (validated R6/R8/R9/R10):
constexpr float FR[L_] = {  // mu = 620
    6.252150e-05f, 1.904358e-04f, 5.418690e-04f, 1.440515e-03f, 3.577400e-03f,
    8.299750e-03f, 1.798893e-02f, 3.642490e-02f, 6.890060e-02f, 1.217600e-01f,
    2.010120e-01f, 3.100190e-01f, 4.466857e-01f, 6.012587e-01f, 7.560710e-01f,
    8.881955e-01f, 9.747661e-01f, 9.993953e-01f, 9.572367e-01f, 8.565352e-01f,
    7.160078e-01f, 5.591580e-01f, 4.079402e-01f, 2.780373e-01f};
constexpr float FG[L_] = {  // mu = 550
    1.110900e-02f, 2.348440e-02f, 4.638000e-02f, 8.557090e-02f, 1.474900e-01f,
    2.374920e-01f, 3.572560e-01f, 5.020580e-01f, 6.591400e-01f, 8.084270e-01f,
    9.262975e-01f, 9.915296e-01f, 9.915296e-01f, 9.262975e-01f, 8.084270e-01f,
    6.591400e-01f, 5.020580e-01f, 3.572560e-01f, 2.374920e-01f, 1.474900e-01f,
    8.557090e-02f, 4.638000e-02f, 2.348440e-02f, 1.110900e-02f};
constexpr float FB[L_] = {  // mu = 450 (pairs with wb)
    6.065307e-01f, 7.609727e-01f, 8.919300e-01f, 9.766475e-01f, 9.990553e-01f,
    9.547420e-01f, 8.523698e-01f, 7.109096e-01f, 5.539184e-01f, 4.032022e-01f,
    2.741855e-01f, 1.741852e-01f, 1.033776e-01f, 5.731640e-02f, 2.968800e-02f,
    1.436580e-02f, 6.494090e-03f, 2.742560e-03f, 1.079230e-03f, 3.988070e-04f,
    1.369660e-04f, 4.417250e-05f, 1.327420e-05f, 3.726650e-06f};
constexpr float FC[L_] = {  // mu = 500 (pairs with wc)
    1.353353e-01f, 2.204053e-01f, 3.353338e-01f, 4.766271e-01f, 6.328849e-01f,
    7.850828e-01f, 9.098110e-01f, 9.849909e-01f, 9.962264e-01f, 9.413024e-01f,
    8.308921e-01f, 6.851808e-01f, 5.278508e-01f, 3.798934e-01f, 2.554222e-01f,
    1.604349e-01f, 9.414200e-02f, 5.160780e-02f, 2.642960e-02f, 1.264440e-02f,
    5.651680e-03f, 2.359870e-03f, 9.205430e-04f, 3.354630e-04f};

__device__ __forceinline__ float fdot2(h2 a, h2 b, float c) {
    return __builtin_amdgcn_fdot2(a, b, c, false);
}

// R25 = R21 (91.6us, no spill, VGPR 232) + three stall fixes. Empirical laws
// locked in: (1) VGPR budget = 65536/wg_size, attributes inert; (2) exactly
// ONE workgroup/CU ever resident (occupancy ~ wg waves across ALL configs).
// So wg=256 (only no-spill point) and attack intra-block stalls:
//  a) weights staging unroll 2 (was unroll 1 = 22 serial HBM rounds ~8us/blk)
//  b) Y double-buffered (2 planes, +4.5KB; co-residency moot)
//  c) merged phases [B(sq) || A(sq+1)]: one barrier per sq (13->8) and B's
//     LDS-latency hides under A's compute in one scheduling region.
// Falsifiers: WRITE >40MB = merge-induced spill (split with sched_barrier);
// dur ~90 + VALUBusy ~25% = compiler didn't interleave (manual next).
__global__ __launch_bounds__(256)
void cassi_fused(
    const float* __restrict__ x,
    const float* __restrict__ wr, const float* __restrict__ wg,
    const float* __restrict__ wb, const float* __restrict__ wc,
    float* __restrict__ out, float* __restrict__ bmax_out)
{
    __shared__ __align__(16) char lds_raw[LDS_BYTES];
    h4* A4  = reinterpret_cast<h4*>(lds_raw);
    h2* XT2 = reinterpret_cast<h2*>(lds_raw) + XT_OFF_H2;
    h4* Y4  = reinterpret_cast<h4*>(lds_raw) + Y_OFF_H4;
    h8* Y8  = reinterpret_cast<h8*>(lds_raw) + Y_OFF_H8;
    float* wmax = reinterpret_cast<float*>(lds_raw + WMAX_OFF);

    const int t  = threadIdx.x;          // 0..255: column
    const int m  = blockIdx.x >> 1;      // row
    const int bp = blockIdx.x & 1;       // b-pair: handles b = 2bp, 2bp+1
    const int b0 = 2 * bp, b1 = 2 * bp + 1;

    // ---- Staging ----
    // zero A pad rows s=22,23 (514 h4): 256 threads x2 + 2 guarded.
    {
        h4 z; z.x = z.y = z.z = z.w = (_Float16)0.f;
        A4[S_ * AP_ + t] = z;
        A4[S_ * AP_ + 256 + t] = z;
        if (t < 2) A4[S_ * AP_ + 512 + t] = z;
    }
    // x: thread t stages column n=t for THIS block's two b -> XT2[n][l] h2.
    {
        const float4* xa = reinterpret_cast<const float4*>(x + ((b0 * M_ + m) * N_ + t) * L_);
        const float4* xb = reinterpret_cast<const float4*>(x + ((b1 * M_ + m) * N_ + t) * L_);
        #pragma unroll
        for (int i = 0; i < 6; ++i) {
            const float4 va = xa[i], vb = xb[i];
            h2 c0; c0.x=(_Float16)va.x; c0.y=(_Float16)vb.x;
            h2 c1; c1.x=(_Float16)va.y; c1.y=(_Float16)vb.y;
            h2 c2; c2.x=(_Float16)va.z; c2.y=(_Float16)vb.z;
            h2 c3; c3.x=(_Float16)va.w; c3.y=(_Float16)vb.w;
            XT2[t * XTP_ + 4 * i + 0] = c0;
            XT2[t * XTP_ + 4 * i + 1] = c1;
            XT2[t * XTP_ + 4 * i + 2] = c2;
            XT2[t * XTP_ + 4 * i + 3] = c3;
        }
    }
    // weights: coalesced, normalized once, h4-packed A[s][n]. unroll 2 so
    // loads of adjacent iterations pipeline (was the ~8us serial-HBM cost).
    {
        const float* wrm = wr + m * (N_ * S_);
        const float* wgm = wg + m * (N_ * S_);
        const float* wbm = wb + m * (N_ * S_);
        const float* wcm = wc + m * (N_ * S_);
        #pragma unroll 2
        for (int i = 0; i < S_; ++i) {
            const int f = i * 256 + t;
            const float r = wrm[f], g = wgm[f], u = wbm[f], v = wcm[f];
            const int n = f / S_, s = f - n * S_;
            const float inv = 1.f / (r + g + u + v);
            h4 p;
            p.x = (_Float16)(r * inv); p.y = (_Float16)(g * inv);
            p.z = (_Float16)(u * inv); p.w = (_Float16)(v * inv);
            A4[s * AP_ + n] = p;
        }
    }
    __syncthreads();

    // ---- A-pass generator (plane pl <- sq). Wave 0 (t<64) dual main+tail;
    // waves 1-3 lean (idx = t-l always >= 41). Wave-uniform branch.
    auto passA = [&](const int sq, const int pl) {
        if (t < 64) {
            float4 aM0, aM1, aT0, aT1;
            aM0.x=aM0.y=aM0.z=aM0.w=0.f; aM1=aM0; aT0=aM0; aT1=aM0;
            #pragma unroll
            for (int l = 0; l < L_; ++l) {
                h2 f01; f01.x = (_Float16)FR[l]; f01.y = (_Float16)FG[l];
                h2 f23; f23.x = (_Float16)FB[l]; f23.y = (_Float16)FC[l];
                const bool mn = (l <= t);
                const int idx = mn ? (t - l) : (256 + t - l);
                const float mm = mn ? 1.f : 0.f;
                const int ab = (4 * sq) * AP_ + idx;
                const h4 p0 = A4[ab], p1 = A4[ab + AP_], p2 = A4[ab + 2 * AP_], p3 = A4[ab + 3 * AP_];
                const h2 xq = XT2[idx * XTP_ + l];
                const float g0 = fdot2(h2{p0.x,p0.y}, f01, fdot2(h2{p0.z,p0.w}, f23, 0.f));
                const float g1 = fdot2(h2{p1.x,p1.y}, f01, fdot2(h2{p1.z,p1.w}, f23, 0.f));
                const float g2 = fdot2(h2{p2.x,p2.y}, f01, fdot2(h2{p2.z,p2.w}, f23, 0.f));
                const float g3 = fdot2(h2{p3.x,p3.y}, f01, fdot2(h2{p3.z,p3.w}, f23, 0.f));
                const float gm0 = g0 * mm, gt0 = g0 - gm0;
                const float gm1 = g1 * mm, gt1 = g1 - gm1;
                const float gm2 = g2 * mm, gt2 = g2 - gm2;
                const float gm3 = g3 * mm, gt3 = g3 - gm3;
                const float xv0 = (float)xq.x, xv1 = (float)xq.y;
                aM0.x += gm0 * xv0; aT0.x += gt0 * xv0;
                aM0.y += gm1 * xv0; aT0.y += gt1 * xv0;
                aM0.z += gm2 * xv0; aT0.z += gt2 * xv0;
                aM0.w += gm3 * xv0; aT0.w += gt3 * xv0;
                aM1.x += gm0 * xv1; aT1.x += gt0 * xv1;
                aM1.y += gm1 * xv1; aT1.y += gt1 * xv1;
                aM1.z += gm2 * xv1; aT1.z += gt2 * xv1;
                aM1.w += gm3 * xv1; aT1.w += gt3 * xv1;
            }
            h4 pm0, pm1;
            pm0.x=(_Float16)aM0.x; pm0.y=(_Float16)aM0.y; pm0.z=(_Float16)aM0.z; pm0.w=(_Float16)aM0.w;
            pm1.x=(_Float16)aM1.x; pm1.y=(_Float16)aM1.y; pm1.z=(_Float16)aM1.z; pm1.w=(_Float16)aM1.w;
            Y4[(pl * NYR_ + t) * 2 + 0] = pm0;
            Y4[(pl * NYR_ + t) * 2 + 1] = pm1;
            if (t < 23) {
                h4 pt0, pt1;
                pt0.x=(_Float16)aT0.x; pt0.y=(_Float16)aT0.y; pt0.z=(_Float16)aT0.z; pt0.w=(_Float16)aT0.w;
                pt1.x=(_Float16)aT1.x; pt1.y=(_Float16)aT1.y; pt1.z=(_Float16)aT1.z; pt1.w=(_Float16)aT1.w;
                Y4[(pl * NYR_ + 256 + t) * 2 + 0] = pt0;
                Y4[(pl * NYR_ + 256 + t) * 2 + 1] = pt1;
            }
        } else {
            float4 aM0, aM1;
            aM0.x=aM0.y=aM0.z=aM0.w=0.f; aM1=aM0;
            #pragma unroll
            for (int l = 0; l < L_; ++l) {
                h2 f01; f01.x = (_Float16)FR[l]; f01.y = (_Float16)FG[l];
                h2 f23; f23.x = (_Float16)FB[l]; f23.y = (_Float16)FC[l];
                const int idx = t - l;      // t >= 64 -> always >= 41
                const int ab = (4 * sq) * AP_ + idx;
                const h4 p0 = A4[ab], p1 = A4[ab + AP_], p2 = A4[ab + 2 * AP_], p3 = A4[ab + 3 * AP_];
                const h2 xq = XT2[idx * XTP_ + l];
                const float g0 = fdot2(h2{p0.x,p0.y}, f01, fdot2(h2{p0.z,p0.w}, f23, 0.f));
                const float g1 = fdot2(h2{p1.x,p1.y}, f01, fdot2(h2{p1.z,p1.w}, f23, 0.f));
                const float g2 = fdot2(h2{p2.x,p2.y}, f01, fdot2(h2{p2.z,p2.w}, f23, 0.f));
                const float g3 = fdot2(h2{p3.x,p3.y}, f01, fdot2(h2{p3.z,p3.w}, f23, 0.f));
                const float xv0 = (float)xq.x, xv1 = (float)xq.y;
                aM0.x += g0 * xv0; aM1.x += g0 * xv1;
                aM0.y += g1 * xv0; aM1.y += g1 * xv1;
                aM0.z += g2 * xv0; aM1.z += g2 * xv1;
                aM0.w += g3 * xv0; aM1.w += g3 * xv1;
            }
            h4 pm0, pm1;
            pm0.x=(_Float16)aM0.x; pm0.y=(_Float16)aM0.y; pm0.z=(_Float16)aM0.z; pm0.w=(_Float16)aM0.w;
            pm1.x=(_Float16)aM1.x; pm1.y=(_Float16)aM1.y; pm1.z=(_Float16)aM1.z; pm1.w=(_Float16)aM1.w;
            Y4[(pl * NYR_ + t) * 2 + 0] = pm0;
            Y4[(pl * NYR_ + t) * 2 + 1] = pm1;
        }
    };

    // ---- Pipeline: A(0); bar; { B(sq) || A(sq+1); bar } for sq=0..5.
    float X0[L_], X1[L_];
    #pragma unroll
    for (int l = 0; l < L_; ++l) { X0[l] = 0.f; X1[l] = 0.f; }
    float vmax = 0.f;

    passA(0, 0);
    __syncthreads();

    #pragma unroll 1
    for (int sq = 0; sq < 6; ++sq) {
        // ---- B-pass: X[b][t][l] += this sq's 4 shots (from plane sq&1).
        {
            const int ab = (4 * sq) * AP_ + t;
            const h4 q0 = A4[ab], q1 = A4[ab + AP_], q2 = A4[ab + 2 * AP_], q3 = A4[ab + 3 * AP_];
            const int ybase = (sq & 1) * NYR_ + t;
            #pragma unroll
            for (int l = 0; l < L_; ++l) {
                h2 f01; f01.x = (_Float16)FR[l]; f01.y = (_Float16)FG[l];
                h2 f23; f23.x = (_Float16)FB[l]; f23.y = (_Float16)FC[l];
                const float g0 = fdot2(h2{q0.x,q0.y}, f01, fdot2(h2{q0.z,q0.w}, f23, 0.f));
                const float g1 = fdot2(h2{q1.x,q1.y}, f01, fdot2(h2{q1.z,q1.w}, f23, 0.f));
                const float g2 = fdot2(h2{q2.x,q2.y}, f01, fdot2(h2{q2.z,q2.w}, f23, 0.f));
                const float g3 = fdot2(h2{q3.x,q3.y}, f01, fdot2(h2{q3.z,q3.w}, f23, 0.f));
                h2 G01; G01.x = (_Float16)g0; G01.y = (_Float16)g1;
                h2 G23; G23.x = (_Float16)g2; G23.y = (_Float16)g3;
                const h8 y = Y8[ybase + l];
                X0[l] = fdot2(G01, h2{y[0],y[1]}, fdot2(G23, h2{y[2],y[3]}, X0[l]));
                X1[l] = fdot2(G01, h2{y[4],y[5]}, fdot2(G23, h2{y[6],y[7]}, X1[l]));
            }
        }
        // ---- A-pass for next sq into the other plane (same scheduling
        // region as B: LDS latencies overlap VALU).
        if (sq < 5) passA(sq + 1, (sq + 1) & 1);
        __syncthreads();
    }

    // ---- Output: contiguous 96B burst per (b, row t) + running max.
    {
        float4* o0 = reinterpret_cast<float4*>(out + ((b0 * M_ + m) * N_ + t) * L_);
        float4* o1 = reinterpret_cast<float4*>(out + ((b1 * M_ + m) * N_ + t) * L_);
        #pragma unroll
        for (int i = 0; i < 6; ++i) {
            float4 v0, v1;
            v0.x = X0[4*i+0]; v0.y = X0[4*i+1]; v0.z = X0[4*i+2]; v0.w = X0[4*i+3];
            v1.x = X1[4*i+0]; v1.y = X1[4*i+1]; v1.z = X1[4*i+2]; v1.w = X1[4*i+3];
            vmax = fmaxf(vmax, fmaxf(fmaxf(v0.x, v0.y), fmaxf(v0.z, v0.w)));
            vmax = fmaxf(vmax, fmaxf(fmaxf(v1.x, v1.y), fmaxf(v1.z, v1.w)));
            o0[i] = v0;
            o1[i] = v1;
        }
    }

    #pragma unroll
    for (int off = 32; off > 0; off >>= 1)
        vmax = fmaxf(vmax, __shfl_xor(vmax, off, 64));
    if ((t & 63) == 0) wmax[t >> 6] = vmax;
    __syncthreads();
    if (t == 0)
        bmax_out[blockIdx.x] = fmaxf(fmaxf(wmax[0], wmax[1]), fmaxf(wmax[2], wmax[3]));
}

// Normalize; each block re-reduces the 512 per-block maxes itself.
__global__ __launch_bounds__(256) void cassi_norm(float* __restrict__ out,
                                                  const float* __restrict__ bmax)
{
    __shared__ float wm[4];
    const int t = threadIdx.x;
    float v = fmaxf(bmax[t], bmax[t + 256]);
    #pragma unroll
    for (int off = 32; off > 0; off >>= 1)
        v = fmaxf(v, __shfl_xor(v, off, 64));
    if ((t & 63) == 0) wm[t >> 6] = v;
    __syncthreads();
    const float inv = 1.f / fmaxf(fmaxf(wm[0], wm[1]), fmaxf(wm[2], wm[3]));
    const int i = (blockIdx.x * 256 + t) * 4;
    float4 q = *reinterpret_cast<float4*>(out + i);
    q.x *= inv; q.y *= inv; q.z *= inv; q.w *= inv;
    *reinterpret_cast<float4*>(out + i) = q;
}

extern "C" void kernel_launch(void* const* d_in, const int* in_sizes, int n_in,
                              void* d_out, int out_size, void* d_ws, size_t ws_size,
                              hipStream_t stream) {
    const float* x  = (const float*)d_in[0];
    const float* wr = (const float*)d_in[1];
    const float* wg = (const float*)d_in[2];
    const float* wb = (const float*)d_in[3];
    const float* wc = (const float*)d_in[4];
    float* out  = (float*)d_out;
    float* bmax = (float*)d_ws;          // 512 per-block maxes (2KB)

    cassi_fused<<<2 * M_, 256, 0, stream>>>(x, wr, wg, wb, wc, out, bmax);
    const int n4blocks = (B_ * M_ * N_ * L_) / 4 / 256;     // 6144, exact
    cassi_norm<<<n4blocks, 256, 0, stream>>>(out, bmax);
}

// Round 17
// 162.408 us; speedup vs baseline: 1.3852x; 1.2034x over previous
//
#include <hip/hip_runtime.h>

typedef _Float16 h8 __attribute__((ext_vector_type(8)));
typedef _Float16 h4 __attribute__((ext_vector_type(4)));
typedef _Float16 h2 __attribute__((ext_vector_type(2)));

// Problem constants (reference: B,M,N,L,S,KERN = 4,256,256,24,22,256; KERN==M → tile is identity)
constexpr int B_ = 4, M_ = 256, N_ = 256, L_ = 24, S_ = 22;
constexpr int SP_  = 24;    // shots padded to 24 (2 zero rows) for clean s-quads
constexpr int AP_  = 257;   // A4 [s][n] row pitch in h4 units (odd -> b64 reads 2-way, free)
constexpr int XTP_ = 25;    // XT2 [n][l] row pitch in h2 (4B) cells (25-dword stride, conflict-free)
constexpr int NYR_ = 280;   // Y rows per plane (279 used: 256 main + 23 tail)

// LDS layout (bytes). 1 wg/CU is an empirical law on this harness (R21/R22/
// R24: occupancy == one wg's waves across VGPR 64..232, LDS 65..154KB), so
// LDS up to 160KB is free — Y holds ALL SIX planes.
constexpr int A4_BYTES = SP_ * AP_ * 8;            // 49,344  A[s][n] h4 over c
constexpr int XT_BYTES = N_ * XTP_ * 4;            // 25,600  x[n][l] h2 over this block's b-pair
constexpr int Y_BYTES  = 6 * NYR_ * 16;            // 26,880  SIX Y planes (16B cells: 2 h4)
constexpr int XT_OFF   = A4_BYTES;                 // 49,344
constexpr int Y_OFF    = XT_OFF + XT_BYTES;        // 74,944 (16B-aligned)
constexpr int WMAX_OFF = Y_OFF + Y_BYTES;          // 101,824
constexpr int LDS_BYTES = WMAX_OFF + 32;           // 101,856 <= 163,840
constexpr int XT_OFF_H2 = XT_OFF / 4;              // 12,336
constexpr int Y_OFF_H4  = Y_OFF / 8;               //  9,368
constexpr int Y_OFF_H8  = Y_OFF / 16;              //  4,684

// Color bases as COMPILE-TIME constants (validated R6/R8/R9/R10):
constexpr float FR[L_] = {  // mu = 620
    6.252150e-05f, 1.904358e-04f, 5.418690e-04f, 1.440515e-03f, 3.577400e-03f,
    8.299750e-03f, 1.798893e-02f, 3.642490e-02f, 6.890060e-02f, 1.217600e-01f,
    2.010120e-01f, 3.100190e-01f, 4.466857e-01f, 6.012587e-01f, 7.560710e-01f,
    8.881955e-01f, 9.747661e-01f, 9.993953e-01f, 9.572367e-01f, 8.565352e-01f,
    7.160078e-01f, 5.591580e-01f, 4.079402e-01f, 2.780373e-01f};
constexpr float FG[L_] = {  // mu = 550
    1.110900e-02f, 2.348440e-02f, 4.638000e-02f, 8.557090e-02f, 1.474900e-01f,
    2.374920e-01f, 3.572560e-01f, 5.020580e-01f, 6.591400e-01f, 8.084270e-01f,
    9.262975e-01f, 9.915296e-01f, 9.915296e-01f, 9.262975e-01f, 8.084270e-01f,
    6.591400e-01f, 5.020580e-01f, 3.572560e-01f, 2.374920e-01f, 1.474900e-01f,
    8.557090e-02f, 4.638000e-02f, 2.348440e-02f, 1.110900e-02f};
constexpr float FB[L_] = {  // mu = 450 (pairs with wb)
    6.065307e-01f, 7.609727e-01f, 8.919300e-01f, 9.766475e-01f, 9.990553e-01f,
    9.547420e-01f, 8.523698e-01f, 7.109096e-01f, 5.539184e-01f, 4.032022e-01f,
    2.741855e-01f, 1.741852e-01f, 1.033776e-01f, 5.731640e-02f, 2.968800e-02f,
    1.436580e-02f, 6.494090e-03f, 2.742560e-03f, 1.079230e-03f, 3.988070e-04f,
    1.369660e-04f, 4.417250e-05f, 1.327420e-05f, 3.726650e-06f};
constexpr float FC[L_] = {  // mu = 500 (pairs with wc)
    1.353353e-01f, 2.204053e-01f, 3.353338e-01f, 4.766271e-01f, 6.328849e-01f,
    7.850828e-01f, 9.098110e-01f, 9.849909e-01f, 9.962264e-01f, 9.413024e-01f,
    8.308921e-01f, 6.851808e-01f, 5.278508e-01f, 3.798934e-01f, 2.554222e-01f,
    1.604349e-01f, 9.414200e-02f, 5.160780e-02f, 2.642960e-02f, 1.264440e-02f,
    5.651680e-03f, 2.359870e-03f, 9.205430e-04f, 3.354630e-04f};

__device__ __forceinline__ float fdot2(h2 a, h2 b, float c) {
    return __builtin_amdgcn_fdot2(a, b, c, false);
}

// R26: R25's merged [B||A] phase spilled (WRITE 26->62MB, dur 110) exactly
// as the falsifier predicted — fusing phases into ONE scheduling region
// multiplies live sets. R26 removes barriers WITHOUT merging live ranges:
// A-passes for different sq are independent (different Y planes), and B
// only reads Y. Two mega-phases, ONE barrier between:
//   Phase A: 6 A-passes back-to-back into 6 planes (no barriers; live set
//            = 16 acc + pipeline regs -> ~200 regs of lookahead = deep ILP)
//   bar
//   Phase B: 6 B-passes back-to-back (Y read-only, zero barriers; X[48]
//            + window ~ 120 regs)
// Barriers 13 -> 3. Weights staging unroll 2 (the safe R25 piece). LDS
// 101.9KB (co-residency moot per the 1-wg/CU law). Falsifier: WRITE >40MB
// = A-region hoist-spill; dur ~90 + VALU ~25% = barriers weren't the cost.
__global__ __launch_bounds__(256)
void cassi_fused(
    const float* __restrict__ x,
    const float* __restrict__ wr, const float* __restrict__ wg,
    const float* __restrict__ wb, const float* __restrict__ wc,
    float* __restrict__ out, float* __restrict__ bmax_out)
{
    __shared__ __align__(16) char lds_raw[LDS_BYTES];
    h4* A4  = reinterpret_cast<h4*>(lds_raw);
    h2* XT2 = reinterpret_cast<h2*>(lds_raw) + XT_OFF_H2;
    h4* Y4  = reinterpret_cast<h4*>(lds_raw) + Y_OFF_H4;
    h8* Y8  = reinterpret_cast<h8*>(lds_raw) + Y_OFF_H8;
    float* wmax = reinterpret_cast<float*>(lds_raw + WMAX_OFF);

    const int t  = threadIdx.x;          // 0..255: column
    const int m  = blockIdx.x >> 1;      // row
    const int bp = blockIdx.x & 1;       // b-pair: handles b = 2bp, 2bp+1
    const int b0 = 2 * bp, b1 = 2 * bp + 1;

    // ---- Staging ----
    // zero A pad rows s=22,23 (514 h4): 256 threads x2 + 2 guarded.
    {
        h4 z; z.x = z.y = z.z = z.w = (_Float16)0.f;
        A4[S_ * AP_ + t] = z;
        A4[S_ * AP_ + 256 + t] = z;
        if (t < 2) A4[S_ * AP_ + 512 + t] = z;
    }
    // x: thread t stages column n=t for THIS block's two b -> XT2[n][l] h2.
    {
        const float4* xa = reinterpret_cast<const float4*>(x + ((b0 * M_ + m) * N_ + t) * L_);
        const float4* xb = reinterpret_cast<const float4*>(x + ((b1 * M_ + m) * N_ + t) * L_);
        #pragma unroll
        for (int i = 0; i < 6; ++i) {
            const float4 va = xa[i], vb = xb[i];
            h2 c0; c0.x=(_Float16)va.x; c0.y=(_Float16)vb.x;
            h2 c1; c1.x=(_Float16)va.y; c1.y=(_Float16)vb.y;
            h2 c2; c2.x=(_Float16)va.z; c2.y=(_Float16)vb.z;
            h2 c3; c3.x=(_Float16)va.w; c3.y=(_Float16)vb.w;
            XT2[t * XTP_ + 4 * i + 0] = c0;
            XT2[t * XTP_ + 4 * i + 1] = c1;
            XT2[t * XTP_ + 4 * i + 2] = c2;
            XT2[t * XTP_ + 4 * i + 3] = c3;
        }
    }
    // weights: coalesced, normalized once, h4-packed A[s][n]; unroll 2 so
    // adjacent iterations' loads pipeline.
    {
        const float* wrm = wr + m * (N_ * S_);
        const float* wgm = wg + m * (N_ * S_);
        const float* wbm = wb + m * (N_ * S_);
        const float* wcm = wc + m * (N_ * S_);
        #pragma unroll 2
        for (int i = 0; i < S_; ++i) {
            const int f = i * 256 + t;
            const float r = wrm[f], g = wgm[f], u = wbm[f], v = wcm[f];
            const int n = f / S_, s = f - n * S_;
            const float inv = 1.f / (r + g + u + v);
            h4 p;
            p.x = (_Float16)(r * inv); p.y = (_Float16)(g * inv);
            p.z = (_Float16)(u * inv); p.w = (_Float16)(v * inv);
            A4[s * AP_ + n] = p;
        }
    }
    __syncthreads();

    // ---- Phase A (mega): 6 independent A-passes, plane sq each, NO
    // barriers between. Wave 0 (t<64) dual main+tail; waves 1-3 lean
    // (idx = t-l always >= 41). Wave-uniform branch.
    if (t < 64) {
        #pragma unroll 1
        for (int sq = 0; sq < 6; ++sq) {
            float4 aM0, aM1, aT0, aT1;
            aM0.x=aM0.y=aM0.z=aM0.w=0.f; aM1=aM0; aT0=aM0; aT1=aM0;
            #pragma unroll
            for (int l = 0; l < L_; ++l) {
                h2 f01; f01.x = (_Float16)FR[l]; f01.y = (_Float16)FG[l];
                h2 f23; f23.x = (_Float16)FB[l]; f23.y = (_Float16)FC[l];
                const bool mn = (l <= t);
                const int idx = mn ? (t - l) : (256 + t - l);
                const float mm = mn ? 1.f : 0.f;
                const int ab = (4 * sq) * AP_ + idx;
                const h4 p0 = A4[ab], p1 = A4[ab + AP_], p2 = A4[ab + 2 * AP_], p3 = A4[ab + 3 * AP_];
                const h2 xq = XT2[idx * XTP_ + l];
                const float g0 = fdot2(h2{p0.x,p0.y}, f01, fdot2(h2{p0.z,p0.w}, f23, 0.f));
                const float g1 = fdot2(h2{p1.x,p1.y}, f01, fdot2(h2{p1.z,p1.w}, f23, 0.f));
                const float g2 = fdot2(h2{p2.x,p2.y}, f01, fdot2(h2{p2.z,p2.w}, f23, 0.f));
                const float g3 = fdot2(h2{p3.x,p3.y}, f01, fdot2(h2{p3.z,p3.w}, f23, 0.f));
                const float gm0 = g0 * mm, gt0 = g0 - gm0;
                const float gm1 = g1 * mm, gt1 = g1 - gm1;
                const float gm2 = g2 * mm, gt2 = g2 - gm2;
                const float gm3 = g3 * mm, gt3 = g3 - gm3;
                const float xv0 = (float)xq.x, xv1 = (float)xq.y;
                aM0.x += gm0 * xv0; aT0.x += gt0 * xv0;
                aM0.y += gm1 * xv0; aT0.y += gt1 * xv0;
                aM0.z += gm2 * xv0; aT0.z += gt2 * xv0;
                aM0.w += gm3 * xv0; aT0.w += gt3 * xv0;
                aM1.x += gm0 * xv1; aT1.x += gt0 * xv1;
                aM1.y += gm1 * xv1; aT1.y += gt1 * xv1;
                aM1.z += gm2 * xv1; aT1.z += gt2 * xv1;
                aM1.w += gm3 * xv1; aT1.w += gt3 * xv1;
            }
            h4 pm0, pm1;
            pm0.x=(_Float16)aM0.x; pm0.y=(_Float16)aM0.y; pm0.z=(_Float16)aM0.z; pm0.w=(_Float16)aM0.w;
            pm1.x=(_Float16)aM1.x; pm1.y=(_Float16)aM1.y; pm1.z=(_Float16)aM1.z; pm1.w=(_Float16)aM1.w;
            Y4[(sq * NYR_ + t) * 2 + 0] = pm0;
            Y4[(sq * NYR_ + t) * 2 + 1] = pm1;
            if (t < 23) {
                h4 pt0, pt1;
                pt0.x=(_Float16)aT0.x; pt0.y=(_Float16)aT0.y; pt0.z=(_Float16)aT0.z; pt0.w=(_Float16)aT0.w;
                pt1.x=(_Float16)aT1.x; pt1.y=(_Float16)aT1.y; pt1.z=(_Float16)aT1.z; pt1.w=(_Float16)aT1.w;
                Y4[(sq * NYR_ + 256 + t) * 2 + 0] = pt0;
                Y4[(sq * NYR_ + 256 + t) * 2 + 1] = pt1;
            }
        }
    } else {
        #pragma unroll 1
        for (int sq = 0; sq < 6; ++sq) {
            float4 aM0, aM1;
            aM0.x=aM0.y=aM0.z=aM0.w=0.f; aM1=aM0;
            #pragma unroll
            for (int l = 0; l < L_; ++l) {
                h2 f01; f01.x = (_Float16)FR[l]; f01.y = (_Float16)FG[l];
                h2 f23; f23.x = (_Float16)FB[l]; f23.y = (_Float16)FC[l];
                const int idx = t - l;      // t >= 64 -> always >= 41
                const int ab = (4 * sq) * AP_ + idx;
                const h4 p0 = A4[ab], p1 = A4[ab + AP_], p2 = A4[ab + 2 * AP_], p3 = A4[ab + 3 * AP_];
                const h2 xq = XT2[idx * XTP_ + l];
                const float g0 = fdot2(h2{p0.x,p0.y}, f01, fdot2(h2{p0.z,p0.w}, f23, 0.f));
                const float g1 = fdot2(h2{p1.x,p1.y}, f01, fdot2(h2{p1.z,p1.w}, f23, 0.f));
                const float g2 = fdot2(h2{p2.x,p2.y}, f01, fdot2(h2{p2.z,p2.w}, f23, 0.f));
                const float g3 = fdot2(h2{p3.x,p3.y}, f01, fdot2(h2{p3.z,p3.w}, f23, 0.f));
                const float xv0 = (float)xq.x, xv1 = (float)xq.y;
                aM0.x += g0 * xv0; aM1.x += g0 * xv1;
                aM0.y += g1 * xv0; aM1.y += g1 * xv1;
                aM0.z += g2 * xv0; aM1.z += g2 * xv1;
                aM0.w += g3 * xv0; aM1.w += g3 * xv1;
            }
            h4 pm0, pm1;
            pm0.x=(_Float16)aM0.x; pm0.y=(_Float16)aM0.y; pm0.z=(_Float16)aM0.z; pm0.w=(_Float16)aM0.w;
            pm1.x=(_Float16)aM1.x; pm1.y=(_Float16)aM1.y; pm1.z=(_Float16)aM1.z; pm1.w=(_Float16)aM1.w;
            Y4[(sq * NYR_ + t) * 2 + 0] = pm0;
            Y4[(sq * NYR_ + t) * 2 + 1] = pm1;
        }
    }
    __syncthreads();

    // ---- Phase B (mega): 6 B-passes, Y read-only, NO barriers.
    float X0[L_], X1[L_];
    #pragma unroll
    for (int l = 0; l < L_; ++l) { X0[l] = 0.f; X1[l] = 0.f; }
    float vmax = 0.f;

    #pragma unroll 1
    for (int sq = 0; sq < 6; ++sq) {
        const int ab = (4 * sq) * AP_ + t;
        const h4 q0 = A4[ab], q1 = A4[ab + AP_], q2 = A4[ab + 2 * AP_], q3 = A4[ab + 3 * AP_];
        const int ybase = sq * NYR_ + t;
        #pragma unroll
        for (int l = 0; l < L_; ++l) {
            h2 f01; f01.x = (_Float16)FR[l]; f01.y = (_Float16)FG[l];
            h2 f23; f23.x = (_Float16)FB[l]; f23.y = (_Float16)FC[l];
            const float g0 = fdot2(h2{q0.x,q0.y}, f01, fdot2(h2{q0.z,q0.w}, f23, 0.f));
            const float g1 = fdot2(h2{q1.x,q1.y}, f01, fdot2(h2{q1.z,q1.w}, f23, 0.f));
            const float g2 = fdot2(h2{q2.x,q2.y}, f01, fdot2(h2{q2.z,q2.w}, f23, 0.f));
            const float g3 = fdot2(h2{q3.x,q3.y}, f01, fdot2(h2{q3.z,q3.w}, f23, 0.f));
            h2 G01; G01.x = (_Float16)g0; G01.y = (_Float16)g1;
            h2 G23; G23.x = (_Float16)g2; G23.y = (_Float16)g3;
            const h8 y = Y8[ybase + l];
            X0[l] = fdot2(G01, h2{y[0],y[1]}, fdot2(G23, h2{y[2],y[3]}, X0[l]));
            X1[l] = fdot2(G01, h2{y[4],y[5]}, fdot2(G23, h2{y[6],y[7]}, X1[l]));
        }
    }

    // ---- Output: contiguous 96B burst per (b, row t) + running max.
    {
        float4* o0 = reinterpret_cast<float4*>(out + ((b0 * M_ + m) * N_ + t) * L_);
        float4* o1 = reinterpret_cast<float4*>(out + ((b1 * M_ + m) * N_ + t) * L_);
        #pragma unroll
        for (int i = 0; i < 6; ++i) {
            float4 v0, v1;
            v0.x = X0[4*i+0]; v0.y = X0[4*i+1]; v0.z = X0[4*i+2]; v0.w = X0[4*i+3];
            v1.x = X1[4*i+0]; v1.y = X1[4*i+1]; v1.z = X1[4*i+2]; v1.w = X1[4*i+3];
            vmax = fmaxf(vmax, fmaxf(fmaxf(v0.x, v0.y), fmaxf(v0.z, v0.w)));
            vmax = fmaxf(vmax, fmaxf(fmaxf(v1.x, v1.y), fmaxf(v1.z, v1.w)));
            o0[i] = v0;
            o1[i] = v1;
        }
    }

    #pragma unroll
    for (int off = 32; off > 0; off >>= 1)
        vmax = fmaxf(vmax, __shfl_xor(vmax, off, 64));
    if ((t & 63) == 0) wmax[t >> 6] = vmax;
    __syncthreads();
    if (t == 0)
        bmax_out[blockIdx.x] = fmaxf(fmaxf(wmax[0], wmax[1]), fmaxf(wmax[2], wmax[3]));
}

// Normalize; each block re-reduces the 512 per-block maxes itself.
__global__ __launch_bounds__(256) void cassi_norm(float* __restrict__ out,
                                                  const float* __restrict__ bmax)
{
    __shared__ float wm[4];
    const int t = threadIdx.x;
    float v = fmaxf(bmax[t], bmax[t + 256]);
    #pragma unroll
    for (int off = 32; off > 0; off >>= 1)
        v = fmaxf(v, __shfl_xor(v, off, 64));
    if ((t & 63) == 0) wm[t >> 6] = v;
    __syncthreads();
    const float inv = 1.f / fmaxf(fmaxf(wm[0], wm[1]), fmaxf(wm[2], wm[3]));
    const int i = (blockIdx.x * 256 + t) * 4;
    float4 q = *reinterpret_cast<float4*>(out + i);
    q.x *= inv; q.y *= inv; q.z *= inv; q.w *= inv;
    *reinterpret_cast<float4*>(out + i) = q;
}

extern "C" void kernel_launch(void* const* d_in, const int* in_sizes, int n_in,
                              void* d_out, int out_size, void* d_ws, size_t ws_size,
                              hipStream_t stream) {
    const float* x  = (const float*)d_in[0];
    const float* wr = (const float*)d_in[1];
    const float* wg = (const float*)d_in[2];
    const float* wb = (const float*)d_in[3];
    const float* wc = (const float*)d_in[4];
    float* out  = (float*)d_out;
    float* bmax = (float*)d_ws;          // 512 per-block maxes (2KB)

    cassi_fused<<<2 * M_, 256, 0, stream>>>(x, wr, wg, wb, wc, out, bmax);
    const int n4blocks = (B_ * M_ * N_ * L_) / 4 / 256;     // 6144, exact
    cassi_norm<<<n4blocks, 256, 0, stream>>>(out, bmax);
}